// Round 13
// baseline (186.665 us; speedup 1.0000x reference)
//
#include <hip/hip_runtime.h>
#include <hip/hip_cooperative_groups.h>
#include <math.h>

namespace cg = cooperative_groups;

// WindingEmbedding: rows = 32768 (B=8, S=4096), D=1024, W=8 windings, F=16 feats.
// out[row][d] = ((emb - mu) * rsqrt(var+eps)) * gamma + beta
// emb[row][d] = sum_f feats[row][f] * pw[d][f] + pb[d]
//
// Analytic LayerNorm stats:
//   mu = f.meanW + mean_b ; E[e^2] = f'Mf + 2 f.c + mean_b2 ; var = E[e^2]-mu^2
// with M = (1/D) W'W, meanW = (1/D) W'1, c = (1/D) W'b.
//
// Ledger: NT stores -8..10us (R5/R9); single-block stats = 95us (R6);
// cross-XCD partial-fold by all blocks +8us (R8/R11); spin-flag fences +13us
// (R12); best 3-dispatch = 41.0us (R10) but ~16-20us of that is dispatch gaps
// (output fits L3 -> main is NOT HBM-bound; R6 arithmetic shows main ~13-16us).
// This round: ONE cooperative kernel. Blocks 0..63 write stats partials while
// all 512 blocks stage weights/features (independent); grid.sync(); block 0
// reduces partials->finals in fixed order; grid.sync(); R10-proven main path.
// 512 blocks x 256 thr = 2 blocks/CU co-residency (guaranteed, no VGPR clamp).

#define TWO_PI 6.28318530717958647692f
#define INV_VOCAB (1.0f / 50257.0f)
#define INV_D (1.0f / 1024.0f)
#define ROWS_PB 64
#define PSTRIDE 320
#define NPART 64
#define FINAL_OFF 20480

typedef float f32x4 __attribute__((ext_vector_type(4)));

__global__ void wind_coop(const int* __restrict__ x,
                          const float* __restrict__ winds,
                          const float* __restrict__ pw,
                          const float* __restrict__ pb,
                          const float* __restrict__ gamma,
                          const float* __restrict__ beta,
                          float* __restrict__ ws,
                          float* __restrict__ out) {
  __shared__ __align__(16) float feat[ROWS_PB][20];  // 16B-aligned rows, <=2-way
  __shared__ __align__(16) float Mlds[16][20];
  __shared__ float mwl[16], cl[16], cst[2];
  __shared__ float murs[ROWS_PB][2];

  cg::grid_group grid = cg::this_grid();
  const int tid = threadIdx.x;
  const int bid = blockIdx.x;
  const int row0 = bid * ROWS_PB;

  // ---- Phase 0a: blocks 0..63 produce stats partials (d in [16b,16b+16)) ----
  if (bid < NPART) {
    const int f = tid >> 4, g = tid & 15;
    const int d0 = bid * 16;
    float m = 0.f, mw = 0.f, cc = 0.f, b1 = 0.f, b2 = 0.f;
#pragma unroll
    for (int k = 0; k < 16; ++k) {
      const int d = d0 + k;
      const float wf = pw[d * 16 + f];
      const float wg = pw[d * 16 + g];
      m = fmaf(wf, wg, m);
      if (g == 0) {
        const float bb = pb[d];
        mw += wf;
        cc = fmaf(wf, bb, cc);
        if (f == 0) {
          b1 += bb;
          b2 = fmaf(bb, bb, b2);
        }
      }
    }
    float* p = ws + bid * PSTRIDE;
    p[tid] = m * INV_D;
    if (g == 0) {
      p[256 + f] = mw * INV_D;
      p[272 + f] = cc * INV_D;
      if (f == 0) {
        p[288] = b1 * INV_D;
        p[289] = b2 * INV_D;
      }
    }
  }

  // ---- Phase 0b (all blocks): stage weights + feature tile (stats-independent) ----
  float4 wreg[4][4];
#pragma unroll
  for (int r = 0; r < 4; ++r)
#pragma unroll
    for (int c = 0; c < 4; ++c)
      wreg[r][c] = reinterpret_cast<const float4*>(pw)[(tid * 4 + r) * 4 + c];
  const float4 pbv = reinterpret_cast<const float4*>(pb)[tid];
  const float4 gv = reinterpret_cast<const float4*>(gamma)[tid];
  const float4 bv = reinterpret_cast<const float4*>(beta)[tid];

#pragma unroll
  for (int s = 0; s < 4; ++s) {
    const int slot = tid + s * 256;
    const int r = slot >> 4, jj = slot & 15;
    const float tf = (float)x[row0 + r] * INV_VOCAB;
    float sn, cs;
    sincosf(TWO_PI * tf * winds[jj >> 1], &sn, &cs);
    feat[r][jj] = (jj & 1) ? sn : cs;  // [cos0,sin0,cos1,sin1,...]
  }

  grid.sync();  // partials visible

  // ---- Phase 1: block 0 reduces 64 partials -> finals (fixed order) ----
  if (bid == 0) {
    float s = 0.f;
#pragma unroll
    for (int bb = 0; bb < NPART; ++bb) s += ws[bb * PSTRIDE + tid];
    ws[FINAL_OFF + tid] = s;
    if (tid < 34) {
      float s2 = 0.f;
#pragma unroll
      for (int bb = 0; bb < NPART; ++bb) s2 += ws[bb * PSTRIDE + 256 + tid];
      ws[FINAL_OFF + 256 + tid] = s2;
    }
  }

  grid.sync();  // finals visible

  // ---- Phase 2: stage finals (1.2 KB) ----
  Mlds[tid >> 4][tid & 15] = ws[FINAL_OFF + tid];
  if (tid < 16) mwl[tid] = ws[FINAL_OFF + 256 + tid];
  else if (tid < 32) cl[tid - 16] = ws[FINAL_OFF + 256 + tid];
  else if (tid < 34) cst[tid - 32] = ws[FINAL_OFF + 256 + tid];
  __syncthreads();

  // ---- Phase 3: per-row stats (16-lane groups, 4 rows/thread, in-wave) ----
  {
    const int jj = tid & 15;
    const float mwj = mwl[jj];
    const float cj = cl[jj];
    const f32x4 M0 = *reinterpret_cast<const f32x4*>(&Mlds[jj][0]);
    const f32x4 M1 = *reinterpret_cast<const f32x4*>(&Mlds[jj][4]);
    const f32x4 M2 = *reinterpret_cast<const f32x4*>(&Mlds[jj][8]);
    const f32x4 M3 = *reinterpret_cast<const f32x4*>(&Mlds[jj][12]);
#pragma unroll
    for (int h = 0; h < 4; ++h) {
      const int r = (tid >> 4) + h * 16;
      const f32x4 F0 = *reinterpret_cast<const f32x4*>(&feat[r][0]);
      const f32x4 F1 = *reinterpret_cast<const f32x4*>(&feat[r][4]);
      const f32x4 F2 = *reinterpret_cast<const f32x4*>(&feat[r][8]);
      const f32x4 F3 = *reinterpret_cast<const f32x4*>(&feat[r][12]);
      float acc = 0.f;
      acc = fmaf(M0.x, F0.x, acc); acc = fmaf(M0.y, F0.y, acc);
      acc = fmaf(M0.z, F0.z, acc); acc = fmaf(M0.w, F0.w, acc);
      acc = fmaf(M1.x, F1.x, acc); acc = fmaf(M1.y, F1.y, acc);
      acc = fmaf(M1.z, F1.z, acc); acc = fmaf(M1.w, F1.w, acc);
      acc = fmaf(M2.x, F2.x, acc); acc = fmaf(M2.y, F2.y, acc);
      acc = fmaf(M2.z, F2.z, acc); acc = fmaf(M2.w, F2.w, acc);
      acc = fmaf(M3.x, F3.x, acc); acc = fmaf(M3.y, F3.y, acc);
      acc = fmaf(M3.z, F3.z, acc); acc = fmaf(M3.w, F3.w, acc);
      const float fjj = feat[r][jj];
      float pE = fjj * fmaf(2.f, cj, acc);
      float pM = fjj * mwj;
#pragma unroll
      for (int off = 1; off < 16; off <<= 1) {
        pE += __shfl_xor(pE, off);
        pM += __shfl_xor(pM, off);
      }
      if (jj == 0) {
        const float mu = pM + cst[0];
        const float var = (pE + cst[1]) - mu * mu;
        murs[r][0] = mu;
        murs[r][1] = rsqrtf(var + 1e-5f);
      }
    }
  }
  __syncthreads();

  // ---- Phase 4: main loop, 64 rows x 4 dims/thread, float4 stores ----
  float* o = out + (size_t)row0 * 1024 + tid * 4;
#pragma unroll 2
  for (int r = 0; r < ROWS_PB; ++r) {
    const f32x4 F0 = *reinterpret_cast<const f32x4*>(&feat[r][0]);
    const f32x4 F1 = *reinterpret_cast<const f32x4*>(&feat[r][4]);
    const f32x4 F2 = *reinterpret_cast<const f32x4*>(&feat[r][8]);
    const f32x4 F3 = *reinterpret_cast<const f32x4*>(&feat[r][12]);
    float e[4];
#pragma unroll
    for (int k = 0; k < 4; ++k) {
      float a = (k == 0) ? pbv.x : (k == 1) ? pbv.y : (k == 2) ? pbv.z : pbv.w;
      a = fmaf(wreg[k][0].x, F0.x, a);
      a = fmaf(wreg[k][0].y, F0.y, a);
      a = fmaf(wreg[k][0].z, F0.z, a);
      a = fmaf(wreg[k][0].w, F0.w, a);
      a = fmaf(wreg[k][1].x, F1.x, a);
      a = fmaf(wreg[k][1].y, F1.y, a);
      a = fmaf(wreg[k][1].z, F1.z, a);
      a = fmaf(wreg[k][1].w, F1.w, a);
      a = fmaf(wreg[k][2].x, F2.x, a);
      a = fmaf(wreg[k][2].y, F2.y, a);
      a = fmaf(wreg[k][2].z, F2.z, a);
      a = fmaf(wreg[k][2].w, F2.w, a);
      a = fmaf(wreg[k][3].x, F3.x, a);
      a = fmaf(wreg[k][3].y, F3.y, a);
      a = fmaf(wreg[k][3].z, F3.z, a);
      a = fmaf(wreg[k][3].w, F3.w, a);
      e[k] = a;
    }
    const float mu = murs[r][0];
    const float rs = murs[r][1];
    const float s0 = gv.x * rs, s1 = gv.y * rs, s2 = gv.z * rs, s3 = gv.w * rs;
    f32x4 res;
    res.x = fmaf(e[0], s0, fmaf(-mu, s0, bv.x));
    res.y = fmaf(e[1], s1, fmaf(-mu, s1, bv.y));
    res.z = fmaf(e[2], s2, fmaf(-mu, s2, bv.z));
    res.w = fmaf(e[3], s3, fmaf(-mu, s3, bv.w));
    *reinterpret_cast<f32x4*>(o + (size_t)r * 1024) = res;
  }
}

extern "C" void kernel_launch(void* const* d_in, const int* in_sizes, int n_in,
                              void* d_out, int out_size, void* d_ws, size_t ws_size,
                              hipStream_t stream) {
  const int* x = (const int*)d_in[0];
  const float* winds = (const float*)d_in[1];
  const float* pw = (const float*)d_in[2];
  const float* pb = (const float*)d_in[3];
  const float* gamma = (const float*)d_in[4];
  const float* beta = (const float*)d_in[5];
  float* out = (float*)d_out;
  float* ws = (float*)d_ws;

  const int rows = in_sizes[0];  // 32768
  dim3 grid((unsigned)(rows / ROWS_PB));  // 512 blocks
  dim3 block(256);
  void* args[] = {(void*)&x, (void*)&winds, (void*)&pw, (void*)&pb,
                  (void*)&gamma, (void*)&beta, (void*)&ws, (void*)&out};
  hipLaunchCooperativeKernel((void*)wind_coop, grid, block, args, 0, stream);
}

// Round 14
// 54.380 us; speedup vs baseline: 3.4326x; 3.4326x over previous
//
#include <hip/hip_runtime.h>
#include <math.h>

// WindingEmbedding: rows = 32768 (B=8, S=4096), D=1024, W=8 windings, F=16 feats.
// out[row][d] = ((emb - mu) * rsqrt(var+eps)) * gamma + beta
// emb[row][d] = sum_f feats[row][f] * pw[d][f] + pb[d]
//
// Analytic LayerNorm stats:
//   mu = f.meanW + mean_b ; E[e^2] = f'Mf + 2 f.c + mean_b2 ; var = E[e^2]-mu^2
// with M = (1/D) W'W, meanW = (1/D) W'1, c = (1/D) W'b.
//
// Ledger: NT stores -8..10us (R5/R9); serial-tile single-block stats = 95us
// (R6); all-blocks partial-fold +8..13us (R8/R11); spin-flag fences +13us
// (R12); grid.sync ~70us each (R13!); best = R10 (41us, 3 dispatches).
// This round: TWO dispatches. stats_one = 1 block x 1024 threads, one 4x4
// M-subtile per wave via f32x4 loads (32 load-instrs/thread), 64-lane
// butterfly reduce, lane-0 writes finals. No barriers, no LDS. wind_main
// is R10-verbatim (4 dims/thread, float4 regular stores, finals-only reads).

#define TWO_PI 6.28318530717958647692f
#define INV_VOCAB (1.0f / 50257.0f)
#define INV_D (1.0f / 1024.0f)
#define ROWS_PB 32
#define FINAL_OFF 20480

typedef float f32x4 __attribute__((ext_vector_type(4)));

// ---------- stats: ONE block, 1024 threads, waves own 4x4 M-subtiles ----------
__global__ __launch_bounds__(1024) void stats_one(const float* __restrict__ pw,
                                                  const float* __restrict__ pb,
                                                  float* __restrict__ ws) {
  const int t = threadIdx.x;
  const int w = t >> 6;   // wave 0..15
  const int L = t & 63;   // lane
  const int jq = w >> 2;  // M row-quad
  const int q = w & 3;    // M col-quad

  const f32x4* pw4 = reinterpret_cast<const f32x4*>(pw);

  f32x4 m0 = {0.f, 0.f, 0.f, 0.f}, m1 = m0, m2 = m0, m3 = m0;
  f32x4 mwv = m0, cv = m0;
  float b1 = 0.f, b2 = 0.f;

#pragma unroll
  for (int k = 0; k < 16; ++k) {
    const int d = L + 64 * k;              // each wave covers all 1024 rows
    const f32x4 wfv = pw4[d * 4 + jq];     // cols 4*jq..4*jq+3 of row d
    const f32x4 wv = pw4[d * 4 + q];       // cols 4*q ..4*q+3
    m0 += wv * wfv.x;
    m1 += wv * wfv.y;
    m2 += wv * wfv.z;
    m3 += wv * wfv.w;
    if (jq == q) {                         // diagonal waves also do vectors
      mwv += wfv;
      const float bb = pb[d];
      cv += wfv * bb;
      if (w == 0) {
        b1 += bb;
        b2 = fmaf(bb, bb, b2);
      }
    }
  }

  // 64-lane butterfly reduction (fixed order -> deterministic)
#pragma unroll
  for (int off = 1; off < 64; off <<= 1) {
#pragma unroll
    for (int c = 0; c < 4; ++c) {
      m0[c] += __shfl_xor(m0[c], off);
      m1[c] += __shfl_xor(m1[c], off);
      m2[c] += __shfl_xor(m2[c], off);
      m3[c] += __shfl_xor(m3[c], off);
      mwv[c] += __shfl_xor(mwv[c], off);
      cv[c] += __shfl_xor(cv[c], off);
    }
    b1 += __shfl_xor(b1, off);
    b2 += __shfl_xor(b2, off);
  }

  if (L == 0) {
    const int rb = jq * 4, cb = q * 4;
#pragma unroll
    for (int c = 0; c < 4; ++c) {
      ws[FINAL_OFF + (rb + 0) * 16 + cb + c] = m0[c] * INV_D;
      ws[FINAL_OFF + (rb + 1) * 16 + cb + c] = m1[c] * INV_D;
      ws[FINAL_OFF + (rb + 2) * 16 + cb + c] = m2[c] * INV_D;
      ws[FINAL_OFF + (rb + 3) * 16 + cb + c] = m3[c] * INV_D;
    }
    if (jq == q) {
#pragma unroll
      for (int c = 0; c < 4; ++c) {
        ws[FINAL_OFF + 256 + rb + c] = mwv[c] * INV_D;  // meanW
        ws[FINAL_OFF + 272 + rb + c] = cv[c] * INV_D;   // c
      }
      if (w == 0) {
        ws[FINAL_OFF + 288] = b1 * INV_D;  // mean_b
        ws[FINAL_OFF + 289] = b2 * INV_D;  // mean_b2
      }
    }
  }
}

// ---------- main: 1024 row-blocks, 256 thr, 4 dims/thread (R10 verbatim) ----------
__global__ __launch_bounds__(256) void wind_main(const int* __restrict__ x,
                                                 const float* __restrict__ winds,
                                                 const float* __restrict__ pw,
                                                 const float* __restrict__ pb,
                                                 const float* __restrict__ gamma,
                                                 const float* __restrict__ beta,
                                                 const float* __restrict__ ws,
                                                 float* __restrict__ out) {
  __shared__ __align__(16) float feat[ROWS_PB][20];  // stride 20: 16B-aligned, <=2-way
  __shared__ __align__(16) float Mlds[16][20];       // b128-loadable rows
  __shared__ float mwl[16], cl[16], cst[2];
  __shared__ float murs[ROWS_PB][2];

  const int tid = threadIdx.x;
  const int row0 = blockIdx.x * ROWS_PB;

  // stage analytic-stats finals (1.2 KB)
  Mlds[tid >> 4][tid & 15] = ws[FINAL_OFF + tid];
  if (tid < 16) mwl[tid] = ws[FINAL_OFF + 256 + tid];
  else if (tid < 32) cl[tid - 16] = ws[FINAL_OFF + 256 + tid];
  else if (tid < 34) cst[tid - 32] = ws[FINAL_OFF + 256 + tid];

  // this thread's 4 projection rows (dims 4t..4t+3) + bias/affine
  float4 wreg[4][4];
#pragma unroll
  for (int r = 0; r < 4; ++r)
#pragma unroll
    for (int c = 0; c < 4; ++c)
      wreg[r][c] = reinterpret_cast<const float4*>(pw)[(tid * 4 + r) * 4 + c];
  const float4 pbv = reinterpret_cast<const float4*>(pb)[tid];
  const float4 gv = reinterpret_cast<const float4*>(gamma)[tid];
  const float4 bv = reinterpret_cast<const float4*>(beta)[tid];

  // feature tile: 32 rows x 16 feats, 2 slots (sincos) per thread
#pragma unroll
  for (int s = 0; s < 2; ++s) {
    const int slot = tid + s * 256;
    const int r = slot >> 4, jj = slot & 15;
    const float tf = (float)x[row0 + r] * INV_VOCAB;
    float sn, cs;
    sincosf(TWO_PI * tf * winds[jj >> 1], &sn, &cs);
    feat[r][jj] = (jj & 1) ? sn : cs;  // [cos0,sin0,cos1,sin1,...]
  }
  __syncthreads();

  // per-row stats: 16-lane group per row, 2 rows per thread, in-wave shuffle
  {
    const int jj = tid & 15;
    const float mwj = mwl[jj];
    const float cj = cl[jj];
    const f32x4 M0 = *reinterpret_cast<const f32x4*>(&Mlds[jj][0]);
    const f32x4 M1 = *reinterpret_cast<const f32x4*>(&Mlds[jj][4]);
    const f32x4 M2 = *reinterpret_cast<const f32x4*>(&Mlds[jj][8]);
    const f32x4 M3 = *reinterpret_cast<const f32x4*>(&Mlds[jj][12]);
#pragma unroll
    for (int h = 0; h < 2; ++h) {
      const int r = (tid >> 4) + h * 16;
      const f32x4 F0 = *reinterpret_cast<const f32x4*>(&feat[r][0]);
      const f32x4 F1 = *reinterpret_cast<const f32x4*>(&feat[r][4]);
      const f32x4 F2 = *reinterpret_cast<const f32x4*>(&feat[r][8]);
      const f32x4 F3 = *reinterpret_cast<const f32x4*>(&feat[r][12]);
      float acc = 0.f;
      acc = fmaf(M0.x, F0.x, acc); acc = fmaf(M0.y, F0.y, acc);
      acc = fmaf(M0.z, F0.z, acc); acc = fmaf(M0.w, F0.w, acc);
      acc = fmaf(M1.x, F1.x, acc); acc = fmaf(M1.y, F1.y, acc);
      acc = fmaf(M1.z, F1.z, acc); acc = fmaf(M1.w, F1.w, acc);
      acc = fmaf(M2.x, F2.x, acc); acc = fmaf(M2.y, F2.y, acc);
      acc = fmaf(M2.z, F2.z, acc); acc = fmaf(M2.w, F2.w, acc);
      acc = fmaf(M3.x, F3.x, acc); acc = fmaf(M3.y, F3.y, acc);
      acc = fmaf(M3.z, F3.z, acc); acc = fmaf(M3.w, F3.w, acc);
      const float fjj = feat[r][jj];
      float pE = fjj * fmaf(2.f, cj, acc);
      float pM = fjj * mwj;
#pragma unroll
      for (int off = 1; off < 16; off <<= 1) {
        pE += __shfl_xor(pE, off);
        pM += __shfl_xor(pM, off);
      }
      if (jj == 0) {
        const float mu = pM + cst[0];
        const float var = (pE + cst[1]) - mu * mu;
        murs[r][0] = mu;
        murs[r][1] = rsqrtf(var + 1e-5f);
      }
    }
  }
  __syncthreads();

  // main loop: 32 rows x 4 dims/thread; broadcast feat reads, float4 stores
  float* o = out + (size_t)row0 * 1024 + tid * 4;
#pragma unroll 2
  for (int r = 0; r < ROWS_PB; ++r) {
    const f32x4 F0 = *reinterpret_cast<const f32x4*>(&feat[r][0]);
    const f32x4 F1 = *reinterpret_cast<const f32x4*>(&feat[r][4]);
    const f32x4 F2 = *reinterpret_cast<const f32x4*>(&feat[r][8]);
    const f32x4 F3 = *reinterpret_cast<const f32x4*>(&feat[r][12]);
    float e[4];
#pragma unroll
    for (int k = 0; k < 4; ++k) {
      float a = (k == 0) ? pbv.x : (k == 1) ? pbv.y : (k == 2) ? pbv.z : pbv.w;
      a = fmaf(wreg[k][0].x, F0.x, a);
      a = fmaf(wreg[k][0].y, F0.y, a);
      a = fmaf(wreg[k][0].z, F0.z, a);
      a = fmaf(wreg[k][0].w, F0.w, a);
      a = fmaf(wreg[k][1].x, F1.x, a);
      a = fmaf(wreg[k][1].y, F1.y, a);
      a = fmaf(wreg[k][1].z, F1.z, a);
      a = fmaf(wreg[k][1].w, F1.w, a);
      a = fmaf(wreg[k][2].x, F2.x, a);
      a = fmaf(wreg[k][2].y, F2.y, a);
      a = fmaf(wreg[k][2].z, F2.z, a);
      a = fmaf(wreg[k][2].w, F2.w, a);
      a = fmaf(wreg[k][3].x, F3.x, a);
      a = fmaf(wreg[k][3].y, F3.y, a);
      a = fmaf(wreg[k][3].z, F3.z, a);
      a = fmaf(wreg[k][3].w, F3.w, a);
      e[k] = a;
    }
    const float mu = murs[r][0];
    const float rs = murs[r][1];
    const float s0 = gv.x * rs, s1 = gv.y * rs, s2 = gv.z * rs, s3 = gv.w * rs;
    f32x4 res;
    res.x = fmaf(e[0], s0, fmaf(-mu, s0, bv.x));
    res.y = fmaf(e[1], s1, fmaf(-mu, s1, bv.y));
    res.z = fmaf(e[2], s2, fmaf(-mu, s2, bv.z));
    res.w = fmaf(e[3], s3, fmaf(-mu, s3, bv.w));
    *reinterpret_cast<f32x4*>(o + (size_t)r * 1024) = res;
  }
}

extern "C" void kernel_launch(void* const* d_in, const int* in_sizes, int n_in,
                              void* d_out, int out_size, void* d_ws, size_t ws_size,
                              hipStream_t stream) {
  const int* x = (const int*)d_in[0];
  const float* winds = (const float*)d_in[1];
  const float* pw = (const float*)d_in[2];
  const float* pb = (const float*)d_in[3];
  const float* gamma = (const float*)d_in[4];
  const float* beta = (const float*)d_in[5];
  float* out = (float*)d_out;
  float* ws = (float*)d_ws;

  const int rows = in_sizes[0];  // 32768
  stats_one<<<1, 1024, 0, stream>>>(pw, pb, ws);
  wind_main<<<rows / ROWS_PB, 256, 0, stream>>>(x, winds, pw, pb, gamma, beta,
                                                ws, out);
}

// Round 15
// 40.605 us; speedup vs baseline: 4.5971x; 1.3392x over previous
//
#include <hip/hip_runtime.h>
#include <math.h>

// WindingEmbedding: rows = 32768 (B=8, S=4096), D=1024, W=8 windings, F=16 feats.
// out[row][d] = ((emb - mu) * rsqrt(var+eps)) * gamma + beta
// emb[row][d] = sum_f feats[row][f] * pw[d][f] + pb[d]
//
// Analytic LayerNorm stats:
//   mu = f.meanW + mean_b ; E[e^2] = f'Mf + 2 f.c + mean_b2 ; var = E[e^2]-mu^2
// with M = (1/D) W'W, meanW = (1/D) W'1, c = (1/D) W'b.
//
// Ledger: NT stores -8..10us (R5/R9); 1-CU serial stats 95us (R6); all-blocks
// partial-fold +8us (R8/R11); spin-flags +13us (R12); grid.sync ~70us (R13);
// 1-CU gather-load stats +13us (R14). Best = R10 (41.0us): partials(64blk) ->
// reduce(1blk) -> main reads 1.2KB finals. This round: R10 with main at
// 512 blocks x 64 rows (R9's correct main minus its NT stores) — halves
// per-block fixed costs; inner loop identical.

#define TWO_PI 6.28318530717958647692f
#define INV_VOCAB (1.0f / 50257.0f)
#define INV_D (1.0f / 1024.0f)
#define ROWS_PB 64
#define PSTRIDE 320
#define FINAL_OFF 20480

typedef float f32x4 __attribute__((ext_vector_type(4)));

// ---------- stats partial: 64 blocks, block b covers d in [16b, 16b+16) ----------
__global__ __launch_bounds__(256) void stats_partial(const float* __restrict__ pw,
                                                     const float* __restrict__ pb,
                                                     float* __restrict__ ws) {
  const int t = threadIdx.x;
  const int b = blockIdx.x;
  const int f = t >> 4, g = t & 15;
  const int d0 = b * 16;

  float m = 0.f, mw = 0.f, cc = 0.f, b1 = 0.f, b2 = 0.f;
#pragma unroll
  for (int k = 0; k < 16; ++k) {
    const int d = d0 + k;
    const float wf = pw[d * 16 + f];
    const float wg = pw[d * 16 + g];
    m = fmaf(wf, wg, m);
    if (g == 0) {
      const float bb = pb[d];
      mw += wf;
      cc = fmaf(wf, bb, cc);
      if (f == 0) {
        b1 += bb;
        b2 = fmaf(bb, bb, b2);
      }
    }
  }
  float* p = ws + b * PSTRIDE;
  p[t] = m * INV_D;
  if (g == 0) {
    p[256 + f] = mw * INV_D;
    p[272 + f] = cc * INV_D;
    if (f == 0) {
      p[288] = b1 * INV_D;
      p[289] = b2 * INV_D;
    }
  }
}

// ---------- stats reduce: 1 block, 320 threads, 64 partials each ----------
__global__ __launch_bounds__(320) void stats_reduce(float* __restrict__ ws) {
  const int t = threadIdx.x;  // only 0..289 meaningful
  float s = 0.f;
#pragma unroll
  for (int b = 0; b < 64; ++b) s += ws[b * PSTRIDE + t];
  ws[FINAL_OFF + t] = s;
}

// ---------- main: 512 row-blocks, 256 thr, 4 dims/thread, 64 rows ----------
__global__ __launch_bounds__(256) void wind_main(const int* __restrict__ x,
                                                 const float* __restrict__ winds,
                                                 const float* __restrict__ pw,
                                                 const float* __restrict__ pb,
                                                 const float* __restrict__ gamma,
                                                 const float* __restrict__ beta,
                                                 const float* __restrict__ ws,
                                                 float* __restrict__ out) {
  __shared__ __align__(16) float feat[ROWS_PB][20];  // stride 20: 16B-aligned, <=2-way
  __shared__ __align__(16) float Mlds[16][20];       // b128-loadable rows
  __shared__ float mwl[16], cl[16], cst[2];
  __shared__ float murs[ROWS_PB][2];

  const int tid = threadIdx.x;
  const int row0 = blockIdx.x * ROWS_PB;

  // stage analytic-stats finals (1.2 KB)
  Mlds[tid >> 4][tid & 15] = ws[FINAL_OFF + tid];
  if (tid < 16) mwl[tid] = ws[FINAL_OFF + 256 + tid];
  else if (tid < 32) cl[tid - 16] = ws[FINAL_OFF + 256 + tid];
  else if (tid < 34) cst[tid - 32] = ws[FINAL_OFF + 256 + tid];

  // this thread's 4 projection rows (dims 4t..4t+3) + bias/affine
  float4 wreg[4][4];
#pragma unroll
  for (int r = 0; r < 4; ++r)
#pragma unroll
    for (int c = 0; c < 4; ++c)
      wreg[r][c] = reinterpret_cast<const float4*>(pw)[(tid * 4 + r) * 4 + c];
  const float4 pbv = reinterpret_cast<const float4*>(pb)[tid];
  const float4 gv = reinterpret_cast<const float4*>(gamma)[tid];
  const float4 bv = reinterpret_cast<const float4*>(beta)[tid];

  // feature tile: 64 rows x 16 feats, 4 slots (sincos) per thread
#pragma unroll
  for (int s = 0; s < 4; ++s) {
    const int slot = tid + s * 256;
    const int r = slot >> 4, jj = slot & 15;
    const float tf = (float)x[row0 + r] * INV_VOCAB;
    float sn, cs;
    sincosf(TWO_PI * tf * winds[jj >> 1], &sn, &cs);
    feat[r][jj] = (jj & 1) ? sn : cs;  // [cos0,sin0,cos1,sin1,...]
  }
  __syncthreads();

  // per-row stats: 16-lane group per row, 4 rows per thread, in-wave shuffle
  {
    const int jj = tid & 15;
    const float mwj = mwl[jj];
    const float cj = cl[jj];
    const f32x4 M0 = *reinterpret_cast<const f32x4*>(&Mlds[jj][0]);
    const f32x4 M1 = *reinterpret_cast<const f32x4*>(&Mlds[jj][4]);
    const f32x4 M2 = *reinterpret_cast<const f32x4*>(&Mlds[jj][8]);
    const f32x4 M3 = *reinterpret_cast<const f32x4*>(&Mlds[jj][12]);
#pragma unroll
    for (int h = 0; h < 4; ++h) {
      const int r = (tid >> 4) + h * 16;
      const f32x4 F0 = *reinterpret_cast<const f32x4*>(&feat[r][0]);
      const f32x4 F1 = *reinterpret_cast<const f32x4*>(&feat[r][4]);
      const f32x4 F2 = *reinterpret_cast<const f32x4*>(&feat[r][8]);
      const f32x4 F3 = *reinterpret_cast<const f32x4*>(&feat[r][12]);
      float acc = 0.f;
      acc = fmaf(M0.x, F0.x, acc); acc = fmaf(M0.y, F0.y, acc);
      acc = fmaf(M0.z, F0.z, acc); acc = fmaf(M0.w, F0.w, acc);
      acc = fmaf(M1.x, F1.x, acc); acc = fmaf(M1.y, F1.y, acc);
      acc = fmaf(M1.z, F1.z, acc); acc = fmaf(M1.w, F1.w, acc);
      acc = fmaf(M2.x, F2.x, acc); acc = fmaf(M2.y, F2.y, acc);
      acc = fmaf(M2.z, F2.z, acc); acc = fmaf(M2.w, F2.w, acc);
      acc = fmaf(M3.x, F3.x, acc); acc = fmaf(M3.y, F3.y, acc);
      acc = fmaf(M3.z, F3.z, acc); acc = fmaf(M3.w, F3.w, acc);
      const float fjj = feat[r][jj];
      float pE = fjj * fmaf(2.f, cj, acc);
      float pM = fjj * mwj;
#pragma unroll
      for (int off = 1; off < 16; off <<= 1) {
        pE += __shfl_xor(pE, off);
        pM += __shfl_xor(pM, off);
      }
      if (jj == 0) {
        const float mu = pM + cst[0];
        const float var = (pE + cst[1]) - mu * mu;
        murs[r][0] = mu;
        murs[r][1] = rsqrtf(var + 1e-5f);
      }
    }
  }
  __syncthreads();

  // main loop: 64 rows x 4 dims/thread; broadcast feat reads, float4 stores
  float* o = out + (size_t)row0 * 1024 + tid * 4;
#pragma unroll 2
  for (int r = 0; r < ROWS_PB; ++r) {
    const f32x4 F0 = *reinterpret_cast<const f32x4*>(&feat[r][0]);
    const f32x4 F1 = *reinterpret_cast<const f32x4*>(&feat[r][4]);
    const f32x4 F2 = *reinterpret_cast<const f32x4*>(&feat[r][8]);
    const f32x4 F3 = *reinterpret_cast<const f32x4*>(&feat[r][12]);
    float e[4];
#pragma unroll
    for (int k = 0; k < 4; ++k) {
      float a = (k == 0) ? pbv.x : (k == 1) ? pbv.y : (k == 2) ? pbv.z : pbv.w;
      a = fmaf(wreg[k][0].x, F0.x, a);
      a = fmaf(wreg[k][0].y, F0.y, a);
      a = fmaf(wreg[k][0].z, F0.z, a);
      a = fmaf(wreg[k][0].w, F0.w, a);
      a = fmaf(wreg[k][1].x, F1.x, a);
      a = fmaf(wreg[k][1].y, F1.y, a);
      a = fmaf(wreg[k][1].z, F1.z, a);
      a = fmaf(wreg[k][1].w, F1.w, a);
      a = fmaf(wreg[k][2].x, F2.x, a);
      a = fmaf(wreg[k][2].y, F2.y, a);
      a = fmaf(wreg[k][2].z, F2.z, a);
      a = fmaf(wreg[k][2].w, F2.w, a);
      a = fmaf(wreg[k][3].x, F3.x, a);
      a = fmaf(wreg[k][3].y, F3.y, a);
      a = fmaf(wreg[k][3].z, F3.z, a);
      a = fmaf(wreg[k][3].w, F3.w, a);
      e[k] = a;
    }
    const float mu = murs[r][0];
    const float rs = murs[r][1];
    const float s0 = gv.x * rs, s1 = gv.y * rs, s2 = gv.z * rs, s3 = gv.w * rs;
    f32x4 res;
    res.x = fmaf(e[0], s0, fmaf(-mu, s0, bv.x));
    res.y = fmaf(e[1], s1, fmaf(-mu, s1, bv.y));
    res.z = fmaf(e[2], s2, fmaf(-mu, s2, bv.z));
    res.w = fmaf(e[3], s3, fmaf(-mu, s3, bv.w));
    *reinterpret_cast<f32x4*>(o + (size_t)r * 1024) = res;
  }
}

extern "C" void kernel_launch(void* const* d_in, const int* in_sizes, int n_in,
                              void* d_out, int out_size, void* d_ws, size_t ws_size,
                              hipStream_t stream) {
  const int* x = (const int*)d_in[0];
  const float* winds = (const float*)d_in[1];
  const float* pw = (const float*)d_in[2];
  const float* pb = (const float*)d_in[3];
  const float* gamma = (const float*)d_in[4];
  const float* beta = (const float*)d_in[5];
  float* out = (float*)d_out;
  float* ws = (float*)d_ws;

  const int rows = in_sizes[0];  // 32768
  stats_partial<<<64, 256, 0, stream>>>(pw, pb, ws);
  stats_reduce<<<1, 320, 0, stream>>>(ws);
  wind_main<<<rows / ROWS_PB, 256, 0, stream>>>(x, winds, pw, pb, gamma, beta,
                                                ws, out);
}